// Round 1
// baseline (313.899 us; speedup 1.0000x reference)
//
#include <hip/hip_runtime.h>
#include <math.h>

// Problem constants
#define NB   16
#define HW   65536          // 256*256

// Workspace layout (float offsets)
#define OFF_S    0          // [16][65536] channel-summed 3x3 box / 9  (reused later as Zc)
#define OFF_MN   1048576    // [128] per (b, lbp-channel) min
#define OFF_MX   1048704    // [128] max
#define OFF_HIST 1048832    // [64][64] raw joint histograms
#define OFF_TOT  1052928    // [1] global hist sum (pad to 4)
#define OFF_Y1   1052932    // [16][4][64][56] expanded features (post leaky)
#define OFF_MEAN 1282308    // [64]
#define OFF_ISTD 1282372    // [64]
#define OFF_ZC   0          // [16][64][56][16] coarse post-w_conv values (reuses S region)
// total floats: 1282436  (~5.13 MB)

__device__ __forceinline__ float leakyf(float v) { return v >= 0.f ? v : 0.01f * v; }

// K1: S[b][h][w] = (sum over 3x3 zero-padded neighborhood of (x0+x1+x2)) / 9
__global__ void k_box(const float* __restrict__ x, float* __restrict__ ws)
{
    __shared__ float t[18][20];
    int b  = blockIdx.z;
    int h0 = blockIdx.y * 16, w0 = blockIdx.x * 16;
    int tid = threadIdx.y * 16 + threadIdx.x;
    const float* xb = x + (size_t)b * 3 * HW;
    for (int i = tid; i < 18 * 18; i += 256) {
        int lh = i / 18, lw = i % 18;
        int gh = h0 - 1 + lh, gw = w0 - 1 + lw;
        float v = 0.f;
        if (gh >= 0 && gh < 256 && gw >= 0 && gw < 256) {
            int p = gh * 256 + gw;
            v = xb[p] + xb[HW + p] + xb[2 * HW + p];
        }
        t[lh][lw] = v;
    }
    __syncthreads();
    int ty = threadIdx.y, tx = threadIdx.x;
    float s = 0.f;
    #pragma unroll
    for (int dy = 0; dy < 3; ++dy)
        #pragma unroll
        for (int dx = 0; dx < 3; ++dx)
            s += t[ty + dy][tx + dx];
    ws[OFF_S + b * HW + (h0 + ty) * 256 + (w0 + tx)] = s / 9.0f;
}

// K2: per (b, lbp-channel o) min/max of v = clip(S[p] - S[p+off], lo, hi). block per (b,o).
__global__ void k_minmax(const float* __restrict__ clo, const float* __restrict__ chi,
                         float* ws)
{
    const int doy[8] = {-1, 1, -1, 1, -1, 1, 0, 0};
    const int dox[8] = {-1, 1,  0, 0,  1, -1, 1, -1};
    int bo = blockIdx.x;
    int b = bo >> 3, o = bo & 7;
    int dy = doy[o], dx = dox[o];
    float lo = clo[0], hi = chi[0];
    const float* Sb = ws + OFF_S + b * HW;
    float vmin = 3.4e38f, vmax = -3.4e38f;
    for (int p = threadIdx.x; p < HW; p += 256) {
        int h = p >> 8, w = p & 255;
        int nh = h + dy, nw = w + dx;
        float off = 0.f;
        if (nh >= 0 && nh < 256 && nw >= 0 && nw < 256) off = Sb[nh * 256 + nw];
        float v = fminf(fmaxf(Sb[p] - off, lo), hi);
        vmin = fminf(vmin, v);
        vmax = fmaxf(vmax, v);
    }
    __shared__ float smn[256], smx[256];
    smn[threadIdx.x] = vmin; smx[threadIdx.x] = vmax;
    __syncthreads();
    for (int s = 128; s > 0; s >>= 1) {
        if (threadIdx.x < s) {
            smn[threadIdx.x] = fminf(smn[threadIdx.x], smn[threadIdx.x + s]);
            smx[threadIdx.x] = fmaxf(smx[threadIdx.x], smx[threadIdx.x + s]);
        }
        __syncthreads();
    }
    if (threadIdx.x == 0) {
        ws[OFF_MN + bo] = smn[0];
        ws[OFF_MX + bo] = smx[0];
    }
}

// K3: joint 8x8 histogram per (b, pair g). block per (b,g).
__global__ void k_hist(const float* __restrict__ clo, const float* __restrict__ chi,
                       float* ws)
{
    __shared__ float lh[64 * 64];   // [bin][col]
    const int doy[8] = {-1, 1, -1, 1, -1, 1, 0, 0};
    const int dox[8] = {-1, 1,  0, 0,  1, -1, 1, -1};
    int bg = blockIdx.x;
    int b = bg >> 2, g = bg & 3;
    int dy0 = doy[2 * g], dx0 = dox[2 * g];
    int dy1 = doy[2 * g + 1], dx1 = dox[2 * g + 1];
    float mn0 = ws[OFF_MN + b * 8 + 2 * g],     mx0 = ws[OFF_MX + b * 8 + 2 * g];
    float mn1 = ws[OFF_MN + b * 8 + 2 * g + 1], mx1 = ws[OFF_MX + b * 8 + 2 * g + 1];
    float r0 = mx0 - mn0, r1 = mx1 - mn1;
    float lev0[8], lev1[8];
    #pragma unroll
    for (int q = 0; q < 8; ++q) {
        lev0[q] = __fadd_rn(mn0, __fmul_rn(r0, (float)q * 0.125f));
        lev1[q] = __fadd_rn(mn1, __fmul_rn(r1, (float)q * 0.125f));
    }
    const float* Sb = ws + OFF_S + b * HW;
    for (int i = threadIdx.x; i < 4096; i += 256) lh[i] = 0.f;
    __syncthreads();
    int col = threadIdx.x & 63;
    float lo = clo[0], hi = chi[0];
    for (int p = threadIdx.x; p < HW; p += 256) {
        int h = p >> 8, w = p & 255;
        float off0 = 0.f, off1 = 0.f;
        int nh = h + dy0, nw = w + dx0;
        if (nh >= 0 && nh < 256 && nw >= 0 && nw < 256) off0 = Sb[nh * 256 + nw];
        nh = h + dy1; nw = w + dx1;
        if (nh >= 0 && nh < 256 && nw >= 0 && nw < 256) off1 = Sb[nh * 256 + nw];
        float sc = Sb[p];
        float v0 = fminf(fmaxf(sc - off0, lo), hi);
        float v1 = fminf(fmaxf(sc - off1, lo), hi);
        int i0 = 0, j0 = 0;
        bool ilo = false, jlo = false;
        #pragma unroll
        for (int k = 1; k < 8; ++k) {
            i0 += (v0 >= lev0[k]); ilo |= (v0 == lev0[k]);
            j0 += (v1 >= lev1[k]); jlo |= (v1 == lev1[k]);
        }
        float prod = v0 * v1;
        atomicAdd(&lh[(i0 * 8 + j0) * 64 + col], prod);
        if (ilo)        atomicAdd(&lh[((i0 - 1) * 8 + j0) * 64 + col], prod);
        if (jlo)        atomicAdd(&lh[(i0 * 8 + (j0 - 1)) * 64 + col], prod);
        if (ilo && jlo) atomicAdd(&lh[((i0 - 1) * 8 + (j0 - 1)) * 64 + col], prod);
    }
    __syncthreads();
    if (threadIdx.x < 64) {
        int bin = threadIdx.x;
        float s = 0.f;
        for (int c = 0; c < 64; ++c) s += lh[bin * 64 + ((c + bin) & 63)];
        ws[OFF_HIST + bg * 64 + bin] = s;
    }
}

// K4: global sum of all 4096 hist values
__global__ void k_total(float* ws)
{
    __shared__ float sm[256];
    float s = 0.f;
    for (int i = threadIdx.x; i < 4096; i += 256) s += ws[OFF_HIST + i];
    sm[threadIdx.x] = s;
    __syncthreads();
    for (int k = 128; k > 0; k >>= 1) {
        if (threadIdx.x < k) sm[threadIdx.x] += sm[threadIdx.x + k];
        __syncthreads();
    }
    if (threadIdx.x == 0) ws[OFF_TOT] = sm[0];
}

// K5: expand matmul + leaky; weighted instance-norm stats per (b,g). block per (b,g).
__global__ void k_expand(const float* __restrict__ we, const float* __restrict__ be,
                         float* ws)
{
    int bg = blockIdx.x;
    float total = ws[OFF_TOT];
    float ls = 0.f, lss = 0.f;
    for (int idx = threadIdx.x; idx < 64 * 56; idx += 256) {
        int q = idx / 56, o = idx % 56;
        float fi = (float)(q >> 3), fj = (float)(q & 7);
        float hv = ws[OFF_HIST + bg * 64 + q] / total;
        float y = we[o * 3 + 0] * fi + we[o * 3 + 1] * fj + we[o * 3 + 2] * hv + be[o];
        y = leakyf(y);
        ws[OFF_Y1 + (bg * 64 + q) * 56 + o] = y;
        int cnt = ((32 * (o + 1) + 6) / 7) - ((32 * o + 6) / 7);   // col repeat count (4 or 5)
        float wgt = (float)(4 * cnt);                               // row repeat is exactly 4
        ls  += y * wgt;
        lss += y * y * wgt;
    }
    __shared__ float s1[256], s2[256];
    s1[threadIdx.x] = ls; s2[threadIdx.x] = lss;
    __syncthreads();
    for (int k = 128; k > 0; k >>= 1) {
        if (threadIdx.x < k) { s1[threadIdx.x] += s1[threadIdx.x + k]; s2[threadIdx.x] += s2[threadIdx.x + k]; }
        __syncthreads();
    }
    if (threadIdx.x == 0) {
        float mean = s1[0] / 65536.0f;
        float var  = s2[0] / 65536.0f - mean * mean;
        ws[OFF_MEAN + bg] = mean;
        ws[OFF_ISTD + bg] = 1.0f / sqrtf(var + 1e-5f);
    }
}

// K6: coarse post-w_conv values Zc[b][q][o][c16] (overwrites dead S region)
__global__ void k_zc(const float* __restrict__ wc, const float* __restrict__ bc, float* ws)
{
    int flat = blockIdx.x * 256 + threadIdx.x;   // 917504 total
    int c = flat & 15;
    int rest = flat >> 4;
    int o = rest % 56;
    int rest2 = rest / 56;
    int q = rest2 & 63;
    int b = rest2 >> 6;
    float acc = 0.f;
    #pragma unroll
    for (int g = 0; g < 4; ++g) {
        int bg = b * 4 + g;
        float yn = (ws[OFF_Y1 + (bg * 64 + q) * 56 + o] - ws[OFF_MEAN + bg]) * ws[OFF_ISTD + bg];
        acc += wc[c * 4 + g] * yn;
    }
    ws[OFF_ZC + flat] = leakyf(acc + bc[c]);
}

// K7: final 3x3 conv (zero pad) over piecewise-constant Z + bias + leaky
__global__ void __launch_bounds__(256) k_final(const float* __restrict__ ws,
                                               const float* __restrict__ wf,
                                               const float* __restrict__ bf,
                                               float* __restrict__ out)
{
    __shared__ float swf[144];
    if (threadIdx.x < 144) swf[threadIdx.x] = wf[threadIdx.x];
    __syncthreads();
    int pix = blockIdx.x * 256 + threadIdx.x;
    int wwp = pix & 255, hhp = (pix >> 8) & 255, b = pix >> 16;
    float acc = 0.f;
    #pragma unroll
    for (int kh = 0; kh < 3; ++kh) {
        int h2 = hhp + kh - 1;
        if (h2 < 0 || h2 > 255) continue;
        int qr = h2 >> 2;
        #pragma unroll
        for (int kw = 0; kw < 3; ++kw) {
            int w2 = wwp + kw - 1;
            if (w2 < 0 || w2 > 255) continue;
            int oc = (w2 * 7) >> 5;
            const float* z = ws + OFF_ZC + ((b * 64 + qr) * 56 + oc) * 16;
            #pragma unroll
            for (int c = 0; c < 16; ++c)
                acc += z[c] * swf[c * 9 + kh * 3 + kw];
        }
    }
    out[pix] = leakyf(acc + bf[0]);
}

extern "C" void kernel_launch(void* const* d_in, const int* in_sizes, int n_in,
                              void* d_out, int out_size, void* d_ws, size_t ws_size,
                              hipStream_t stream)
{
    const float* x   = (const float*)d_in[0];
    const float* we  = (const float*)d_in[1];
    const float* be  = (const float*)d_in[2];
    const float* wc  = (const float*)d_in[3];
    const float* bc  = (const float*)d_in[4];
    const float* wf  = (const float*)d_in[5];
    const float* bfi = (const float*)d_in[6];
    const float* clo = (const float*)d_in[7];
    const float* chi = (const float*)d_in[8];
    float* out = (float*)d_out;
    float* ws  = (float*)d_ws;

    dim3 blk(16, 16);
    dim3 grd(16, 16, NB);
    k_box<<<grd, blk, 0, stream>>>(x, ws);
    k_minmax<<<128, 256, 0, stream>>>(clo, chi, ws);
    k_hist<<<64, 256, 0, stream>>>(clo, chi, ws);
    k_total<<<1, 256, 0, stream>>>(ws);
    k_expand<<<64, 256, 0, stream>>>(we, be, ws);
    k_zc<<<3584, 256, 0, stream>>>(wc, bc, ws);
    k_final<<<4096, 256, 0, stream>>>(ws, wf, bfi, out);
}

// Round 2
// 157.962 us; speedup vs baseline: 1.9872x; 1.9872x over previous
//
#include <hip/hip_runtime.h>
#include <math.h>

// Problem constants
#define NB   16
#define HW   65536          // 256*256
#define NCHM 32             // minmax pixel-chunks per batch
#define NCHH 16             // hist pixel-chunks per (b,pair)

// Workspace layout (float offsets)
#define OFF_S    0          // [16][65536] channel-summed 3x3 box / 9  (reused later as Zc)
#define OFF_MN   1048576    // [128] per (b, lbp-channel) min
#define OFF_MX   1048704    // [128] max
#define OFF_HIST 1048832    // [64][64] raw joint histograms
#define OFF_TOT  1052928    // [1] global hist sum (pad to 4)
#define OFF_Y1   1052932    // [16][4][64][56] expanded features (post leaky)
#define OFF_PH   1052932    // [1024][64] partial hists  (overlaps Y1 - dead before k_expand)
#define OFF_PMN  1118468    // [128][32] partial mins    (inside Y1 region, dead before k_expand)
#define OFF_PMX  1122564    // [128][32] partial maxs
#define OFF_MEAN 1282308    // [64]
#define OFF_ISTD 1282372    // [64]
#define OFF_ZC   0          // [16][64][56][16] coarse post-w_conv values (reuses S region)
// total floats: 1282436  (~5.13 MB)

__device__ __forceinline__ float leakyf(float v) { return v >= 0.f ? v : 0.01f * v; }

// K1: S[b][h][w] = (sum over 3x3 zero-padded neighborhood of (x0+x1+x2)) / 9
__global__ void k_box(const float* __restrict__ x, float* __restrict__ ws)
{
    __shared__ float t[18][20];
    int b  = blockIdx.z;
    int h0 = blockIdx.y * 16, w0 = blockIdx.x * 16;
    int tid = threadIdx.y * 16 + threadIdx.x;
    const float* xb = x + (size_t)b * 3 * HW;
    for (int i = tid; i < 18 * 18; i += 256) {
        int lh = i / 18, lw = i % 18;
        int gh = h0 - 1 + lh, gw = w0 - 1 + lw;
        float v = 0.f;
        if (gh >= 0 && gh < 256 && gw >= 0 && gw < 256) {
            int p = gh * 256 + gw;
            v = xb[p] + xb[HW + p] + xb[2 * HW + p];
        }
        t[lh][lw] = v;
    }
    __syncthreads();
    int ty = threadIdx.y, tx = threadIdx.x;
    float s = 0.f;
    #pragma unroll
    for (int dy = 0; dy < 3; ++dy)
        #pragma unroll
        for (int dx = 0; dx < 3; ++dx)
            s += t[ty + dy][tx + dx];
    ws[OFF_S + b * HW + (h0 + ty) * 256 + (w0 + tx)] = s / 9.0f;
}

// K2a: per (b, chunk) partial min/max for all 8 lbp directions at once.
__global__ void k_minmax_part(const float* __restrict__ clo, const float* __restrict__ chi,
                              float* ws)
{
    const int doy[8] = {-1, 1, -1, 1, -1, 1, 0, 0};
    const int dox[8] = {-1, 1,  0, 0,  1, -1, 1, -1};
    int b  = blockIdx.x / NCHM;
    int ch = blockIdx.x % NCHM;
    float lo = clo[0], hi = chi[0];
    const float* Sb = ws + OFF_S + b * HW;
    float vmn[8], vmx[8];
    #pragma unroll
    for (int o = 0; o < 8; ++o) { vmn[o] = 3.4e38f; vmx[o] = -3.4e38f; }
    int base = ch * (HW / NCHM);
    #pragma unroll
    for (int it = 0; it < (HW / NCHM) / 256; ++it) {
        int p = base + it * 256 + threadIdx.x;
        int h = p >> 8, w = p & 255;
        float sc = Sb[p];
        #pragma unroll
        for (int o = 0; o < 8; ++o) {
            int nh = h + doy[o], nw = w + dox[o];
            float off = ((unsigned)nh < 256u && (unsigned)nw < 256u) ? Sb[nh * 256 + nw] : 0.f;
            float v = fminf(fmaxf(sc - off, lo), hi);
            vmn[o] = fminf(vmn[o], v);
            vmx[o] = fmaxf(vmx[o], v);
        }
    }
    // wave butterfly reduce
    #pragma unroll
    for (int o = 0; o < 8; ++o) {
        #pragma unroll
        for (int m = 1; m < 64; m <<= 1) {
            vmn[o] = fminf(vmn[o], __shfl_xor(vmn[o], m));
            vmx[o] = fmaxf(vmx[o], __shfl_xor(vmx[o], m));
        }
    }
    __shared__ float smn[4][8], smx[4][8];
    int wid = threadIdx.x >> 6, lane = threadIdx.x & 63;
    if (lane == 0) {
        #pragma unroll
        for (int o = 0; o < 8; ++o) { smn[wid][o] = vmn[o]; smx[wid][o] = vmx[o]; }
    }
    __syncthreads();
    if (threadIdx.x < 8) {
        int o = threadIdx.x;
        float mn = fminf(fminf(smn[0][o], smn[1][o]), fminf(smn[2][o], smn[3][o]));
        float mx = fmaxf(fmaxf(smx[0][o], smx[1][o]), fmaxf(smx[2][o], smx[3][o]));
        ws[OFF_PMN + (b * 8 + o) * NCHM + ch] = mn;
        ws[OFF_PMX + (b * 8 + o) * NCHM + ch] = mx;
    }
}

// K2b: reduce partials -> MN/MX
__global__ void k_minmax_red(float* ws)
{
    int bo = threadIdx.x;
    if (bo < 128) {
        float mn = 3.4e38f, mx = -3.4e38f;
        for (int c = 0; c < NCHM; ++c) {
            mn = fminf(mn, ws[OFF_PMN + bo * NCHM + c]);
            mx = fmaxf(mx, ws[OFF_PMX + bo * NCHM + c]);
        }
        ws[OFF_MN + bo] = mn;
        ws[OFF_MX + bo] = mx;
    }
}

// K3a: partial joint 8x8 histogram per (b, pair g, chunk).
__global__ void k_hist_part(const float* __restrict__ clo, const float* __restrict__ chi,
                            float* ws)
{
    __shared__ float lh[64 * 64];   // [bin][col]
    const int doy[8] = {-1, 1, -1, 1, -1, 1, 0, 0};
    const int dox[8] = {-1, 1,  0, 0,  1, -1, 1, -1};
    int bg = blockIdx.x / NCHH;
    int ch = blockIdx.x % NCHH;
    int b = bg >> 2, g = bg & 3;
    int dy0 = doy[2 * g], dx0 = dox[2 * g];
    int dy1 = doy[2 * g + 1], dx1 = dox[2 * g + 1];
    float mn0 = ws[OFF_MN + b * 8 + 2 * g],     mx0 = ws[OFF_MX + b * 8 + 2 * g];
    float mn1 = ws[OFF_MN + b * 8 + 2 * g + 1], mx1 = ws[OFF_MX + b * 8 + 2 * g + 1];
    float r0 = mx0 - mn0, r1 = mx1 - mn1;
    float lev0[8], lev1[8];
    #pragma unroll
    for (int q = 0; q < 8; ++q) {
        lev0[q] = __fadd_rn(mn0, __fmul_rn(r0, (float)q * 0.125f));
        lev1[q] = __fadd_rn(mn1, __fmul_rn(r1, (float)q * 0.125f));
    }
    const float* Sb = ws + OFF_S + b * HW;
    for (int i = threadIdx.x; i < 4096; i += 256) lh[i] = 0.f;
    __syncthreads();
    int col = threadIdx.x & 63;
    float lo = clo[0], hi = chi[0];
    int base = ch * (HW / NCHH);
    #pragma unroll
    for (int it = 0; it < (HW / NCHH) / 256; ++it) {
        int p = base + it * 256 + threadIdx.x;
        int h = p >> 8, w = p & 255;
        float off0 = 0.f, off1 = 0.f;
        int nh = h + dy0, nw = w + dx0;
        if ((unsigned)nh < 256u && (unsigned)nw < 256u) off0 = Sb[nh * 256 + nw];
        nh = h + dy1; nw = w + dx1;
        if ((unsigned)nh < 256u && (unsigned)nw < 256u) off1 = Sb[nh * 256 + nw];
        float sc = Sb[p];
        float v0 = fminf(fmaxf(sc - off0, lo), hi);
        float v1 = fminf(fmaxf(sc - off1, lo), hi);
        int i0 = 0, j0 = 0;
        bool ilo = false, jlo = false;
        #pragma unroll
        for (int k = 1; k < 8; ++k) {
            i0 += (v0 >= lev0[k]); ilo |= (v0 == lev0[k]);
            j0 += (v1 >= lev1[k]); jlo |= (v1 == lev1[k]);
        }
        float prod = v0 * v1;
        atomicAdd(&lh[(i0 * 8 + j0) * 64 + col], prod);
        if (ilo)        atomicAdd(&lh[((i0 - 1) * 8 + j0) * 64 + col], prod);
        if (jlo)        atomicAdd(&lh[(i0 * 8 + (j0 - 1)) * 64 + col], prod);
        if (ilo && jlo) atomicAdd(&lh[((i0 - 1) * 8 + (j0 - 1)) * 64 + col], prod);
    }
    __syncthreads();
    if (threadIdx.x < 64) {
        int bin = threadIdx.x;
        float s = 0.f;
        for (int c = 0; c < 64; ++c) s += lh[bin * 64 + ((c + bin) & 63)];
        ws[OFF_PH + blockIdx.x * 64 + bin] = s;
    }
}

// K3b: reduce hist partials over chunks
__global__ void k_hist_red(float* ws)
{
    int idx = blockIdx.x * 256 + threadIdx.x;   // 4096 total
    if (idx < 4096) {
        int bg = idx >> 6, bin = idx & 63;
        float s = 0.f;
        #pragma unroll
        for (int c = 0; c < NCHH; ++c)
            s += ws[OFF_PH + (bg * NCHH + c) * 64 + bin];
        ws[OFF_HIST + idx] = s;
    }
}

// K4: global sum of all 4096 hist values
__global__ void k_total(float* ws)
{
    __shared__ float sm[256];
    float s = 0.f;
    for (int i = threadIdx.x; i < 4096; i += 256) s += ws[OFF_HIST + i];
    sm[threadIdx.x] = s;
    __syncthreads();
    for (int k = 128; k > 0; k >>= 1) {
        if (threadIdx.x < k) sm[threadIdx.x] += sm[threadIdx.x + k];
        __syncthreads();
    }
    if (threadIdx.x == 0) ws[OFF_TOT] = sm[0];
}

// K5: expand matmul + leaky; weighted instance-norm stats per (b,g). block per (b,g).
__global__ void k_expand(const float* __restrict__ we, const float* __restrict__ be,
                         float* ws)
{
    int bg = blockIdx.x;
    float total = ws[OFF_TOT];
    float ls = 0.f, lss = 0.f;
    for (int idx = threadIdx.x; idx < 64 * 56; idx += 256) {
        int q = idx / 56, o = idx % 56;
        float fi = (float)(q >> 3), fj = (float)(q & 7);
        float hv = ws[OFF_HIST + bg * 64 + q] / total;
        float y = we[o * 3 + 0] * fi + we[o * 3 + 1] * fj + we[o * 3 + 2] * hv + be[o];
        y = leakyf(y);
        ws[OFF_Y1 + (bg * 64 + q) * 56 + o] = y;
        int cnt = ((32 * (o + 1) + 6) / 7) - ((32 * o + 6) / 7);   // col repeat count (4 or 5)
        float wgt = (float)(4 * cnt);                               // row repeat is exactly 4
        ls  += y * wgt;
        lss += y * y * wgt;
    }
    __shared__ float s1[256], s2[256];
    s1[threadIdx.x] = ls; s2[threadIdx.x] = lss;
    __syncthreads();
    for (int k = 128; k > 0; k >>= 1) {
        if (threadIdx.x < k) { s1[threadIdx.x] += s1[threadIdx.x + k]; s2[threadIdx.x] += s2[threadIdx.x + k]; }
        __syncthreads();
    }
    if (threadIdx.x == 0) {
        float mean = s1[0] / 65536.0f;
        float var  = s2[0] / 65536.0f - mean * mean;
        ws[OFF_MEAN + bg] = mean;
        ws[OFF_ISTD + bg] = 1.0f / sqrtf(var + 1e-5f);
    }
}

// K6: coarse post-w_conv values Zc[b][q][o][c16] (overwrites dead S region)
__global__ void k_zc(const float* __restrict__ wc, const float* __restrict__ bc, float* ws)
{
    int flat = blockIdx.x * 256 + threadIdx.x;   // 917504 total
    int c = flat & 15;
    int rest = flat >> 4;
    int o = rest % 56;
    int rest2 = rest / 56;
    int q = rest2 & 63;
    int b = rest2 >> 6;
    float acc = 0.f;
    #pragma unroll
    for (int g = 0; g < 4; ++g) {
        int bg = b * 4 + g;
        float yn = (ws[OFF_Y1 + (bg * 64 + q) * 56 + o] - ws[OFF_MEAN + bg]) * ws[OFF_ISTD + bg];
        acc += wc[c * 4 + g] * yn;
    }
    ws[OFF_ZC + flat] = leakyf(acc + bc[c]);
}

// K7: final 3x3 conv (zero pad) over piecewise-constant Z + bias + leaky
__global__ void __launch_bounds__(256) k_final(const float* __restrict__ ws,
                                               const float* __restrict__ wf,
                                               const float* __restrict__ bf,
                                               float* __restrict__ out)
{
    __shared__ float swf[144];
    if (threadIdx.x < 144) swf[threadIdx.x] = wf[threadIdx.x];
    __syncthreads();
    int pix = blockIdx.x * 256 + threadIdx.x;
    int wwp = pix & 255, hhp = (pix >> 8) & 255, b = pix >> 16;
    float acc = 0.f;
    #pragma unroll
    for (int kh = 0; kh < 3; ++kh) {
        int h2 = hhp + kh - 1;
        if (h2 < 0 || h2 > 255) continue;
        int qr = h2 >> 2;
        #pragma unroll
        for (int kw = 0; kw < 3; ++kw) {
            int w2 = wwp + kw - 1;
            if (w2 < 0 || w2 > 255) continue;
            int oc = (w2 * 7) >> 5;
            const float* z = ws + OFF_ZC + ((b * 64 + qr) * 56 + oc) * 16;
            #pragma unroll
            for (int c = 0; c < 16; ++c)
                acc += z[c] * swf[c * 9 + kh * 3 + kw];
        }
    }
    out[pix] = leakyf(acc + bf[0]);
}

extern "C" void kernel_launch(void* const* d_in, const int* in_sizes, int n_in,
                              void* d_out, int out_size, void* d_ws, size_t ws_size,
                              hipStream_t stream)
{
    const float* x   = (const float*)d_in[0];
    const float* we  = (const float*)d_in[1];
    const float* be  = (const float*)d_in[2];
    const float* wc  = (const float*)d_in[3];
    const float* bc  = (const float*)d_in[4];
    const float* wf  = (const float*)d_in[5];
    const float* bfi = (const float*)d_in[6];
    const float* clo = (const float*)d_in[7];
    const float* chi = (const float*)d_in[8];
    float* out = (float*)d_out;
    float* ws  = (float*)d_ws;

    dim3 blk(16, 16);
    dim3 grd(16, 16, NB);
    k_box<<<grd, blk, 0, stream>>>(x, ws);
    k_minmax_part<<<NB * NCHM, 256, 0, stream>>>(clo, chi, ws);
    k_minmax_red<<<1, 256, 0, stream>>>(ws);
    k_hist_part<<<64 * NCHH, 256, 0, stream>>>(clo, chi, ws);
    k_hist_red<<<16, 256, 0, stream>>>(ws);
    k_total<<<1, 256, 0, stream>>>(ws);
    k_expand<<<64, 256, 0, stream>>>(we, be, ws);
    k_zc<<<3584, 256, 0, stream>>>(wc, bc, ws);
    k_final<<<4096, 256, 0, stream>>>(ws, wf, bfi, out);
}